// Round 8
// baseline (381.078 us; speedup 1.0000x reference)
//
#include <hip/hip_runtime.h>

#define L_SEQ 1024
#define DD 4096
#define NC 16   // scan chunks
#define CT 64   // chunk length (NC*CT == L_SEQ)

typedef short bf16x8 __attribute__((ext_vector_type(8)));
typedef float f32x4 __attribute__((ext_vector_type(4)));
typedef unsigned short u16;

typedef const __attribute__((address_space(1))) void gas_t;
typedef __attribute__((address_space(3))) void las_t;

__device__ inline u16 f2bf(float f) {
  unsigned int u = __float_as_uint(f);
  u = (u + 0x7FFFu + ((u >> 16) & 1u)) >> 16;
  return (u16)u;
}

__device__ inline float bf2f(u16 v) {
  return __uint_as_float(((unsigned int)v) << 16);
}

__device__ inline float softplusf(float x) {
  return x > 20.f ? x : log1pf(expf(x));
}

// ---------------- all 5 fp32->bf16 casts in one kernel ---------------------
__global__ __launch_bounds__(256) void cast_all_k(
    const float* __restrict__ hs, const float* __restrict__ w_in,
    const float* __restrict__ xw, const float* __restrict__ dtw,
    const float* __restrict__ ow, u16* __restrict__ hs_bf,
    u16* __restrict__ win_bf, u16* __restrict__ xw_bf,
    u16* __restrict__ dtw_bf, u16* __restrict__ ow_bf) {
  const int blk = blockIdx.x;
  const float* s;
  u16* d;
  int base;
  if (blk < 4096)        { s = hs;   d = hs_bf;  base = blk; }
  else if (blk < 20480)  { s = w_in; d = win_bf; base = blk - 4096; }
  else if (blk < 21120)  { s = xw;   d = xw_bf;  base = blk - 20480; }
  else if (blk < 21632)  { s = dtw;  d = dtw_bf; base = blk - 21120; }
  else                   { s = ow;   d = ow_bf;  base = blk - 21632; }
  const int i = (base * 256 + threadIdx.x) * 4;
  float4 v = *(const float4*)(s + i);
  ushort4 o;
  o.x = f2bf(v.x); o.y = f2bf(v.y); o.z = f2bf(v.z); o.w = f2bf(v.w);
  *(ushort4*)(d + i) = o;
}

// ---------------- reduce 4 fp32 partials -> fp32 out (float4) --------------
__global__ __launch_bounds__(256) void reduce4_k(const float* __restrict__ p,
                                                 float* __restrict__ out,
                                                 long n) {
  long i = ((long)blockIdx.x * 256 + threadIdx.x) * 4;
  if (i >= n) return;
  float4 a = *(const float4*)(p + i);
  float4 b = *(const float4*)(p + n + i);
  float4 c = *(const float4*)(p + 2 * n + i);
  float4 d = *(const float4*)(p + 3 * n + i);
  float4 o;
  o.x = (a.x + b.x) + (c.x + d.x);
  o.y = (a.y + b.y) + (c.y + d.y);
  o.z = (a.z + b.z) + (c.z + d.z);
  o.w = (a.w + b.w) + (c.w + d.w);
  *(float4*)(out + i) = o;
}

// ---------------- x_proj finalize: reduce 8 partials, split ts/ssm ---------
__global__ __launch_bounds__(256) void xproj_fin_k(const float* __restrict__ parts,
                                                   u16* __restrict__ ts,
                                                   float* __restrict__ ssm) {
  const int idx = blockIdx.x * 256 + threadIdx.x;  // < 2048*160
  float s = 0.f;
#pragma unroll
  for (int z = 0; z < 8; z++) s += parts[z * 327680 + idx];
  const int row = idx / 160;
  const int col = idx - row * 160;
  if (col < 128) ts[row * 128 + col] = f2bf(s);
  else ssm[idx] = s;
}

// ============ 256x256 BK=32 dbuf 2-phase MFMA GEMM: C = A[M,K]*B[N,K]^T ====
// 8 waves (2M x 4N), per-wave 128x64 = 8x4 frags of 16x16x32.
// LDS content swizzle (conflict-free, rule #21 both-sides):
//   LDS slot (row, granule g) holds global k-slot g ^ ((row>>1)&3).
//   Staging: linear gload_lds dest; per-thread SOURCE k-slot pre-XORed.
//   Read: granule = kq ^ ((row>>1)&3); constant per thread since frag rows
//   step by 16 (16>>1 ≡ 0 mod 4). Wave covers 64 distinct 16B slots -> 0-way.
// CMODE: 1 = bf16 store, 2 = split-K fp32 partial store (z slice at z*zstride)
template <int CMODE, bool SWZ>
__global__ __launch_bounds__(512, 2) void gemm256(const u16* __restrict__ A,
                                                  const u16* __restrict__ B,
                                                  void* __restrict__ Cv,
                                                  int Nld, int K, int kc,
                                                  long zstride) {
  __shared__ u16 lds[2][2][8192];  // [buf][0=A,1=B][256 rows * 32 k]
  const int tid = threadIdx.x;
  const int lane = tid & 63, wid = tid >> 6;
  const int wm = wid >> 2, wn = wid & 3;
  int ty = blockIdx.y, tx = blockIdx.x;
  if (SWZ) {
    // bijective XCD swizzle for 8(y) x 32(x) grid
    int flat = blockIdx.y * 32 + blockIdx.x;
    int xcd = flat & 7, pos = flat >> 3;
    ty = (xcd & 1) * 4 + (pos >> 3);
    tx = (xcd >> 1) * 8 + (pos & 7);
  }
  const long tm = (long)ty * 256, tn = (long)tx * 256;

  const long ks0 = (CMODE == 2) ? (long)blockIdx.z * kc : 0;

  // staging: thread writes LDS (row = tid>>2, granule = tid&3); source k-slot
  // pre-swizzled so content obeys the slot map above.
  const int srow = tid >> 2;
  const int sks = (((tid & 3) ^ ((srow >> 1) & 3))) * 8;  // u16 offset
  const u16* gA0 = A + (tm + srow) * (long)K + ks0 + sks;
  const u16* gA1 = A + (tm + 128 + srow) * (long)K + ks0 + sks;
  const u16* gB0 = B + (tn + srow) * (long)K + ks0 + sks;
  const u16* gB1 = B + (tn + 128 + srow) * (long)K + ks0 + sks;
  const int sb0 = wid * 512;         // wave-uniform LDS bases (u16 idx)
  const int sb1 = 4096 + wid * 512;

  f32x4 acc[8][4] = {};

  const int lr = lane & 15, kq = lane >> 4;
  const int arow = wm * 128 + lr;
  const int brow = wn * 64 + lr;
  const int granA = (kq ^ ((arow >> 1) & 3)) * 8;  // constant per thread
  const int granB = (kq ^ ((brow >> 1) & 3)) * 8;

  const int KT = kc >> 5;
  int cur = 0;
  // prologue: stage K-tile 0 into buf 0
  __builtin_amdgcn_global_load_lds((gas_t*)gA0, (las_t*)&lds[0][0][sb0], 16, 0, 0);
  __builtin_amdgcn_global_load_lds((gas_t*)gA1, (las_t*)&lds[0][0][sb1], 16, 0, 0);
  __builtin_amdgcn_global_load_lds((gas_t*)gB0, (las_t*)&lds[0][1][sb0], 16, 0, 0);
  __builtin_amdgcn_global_load_lds((gas_t*)gB1, (las_t*)&lds[0][1][sb1], 16, 0, 0);
  __syncthreads();

  for (int kt = 0; kt < KT; ++kt) {
    if (kt + 1 < KT) {  // stage next K-tile into other buffer (async)
      const long ko = (long)(kt + 1) << 5;
      const int nb = cur ^ 1;
      __builtin_amdgcn_global_load_lds((gas_t*)(gA0 + ko), (las_t*)&lds[nb][0][sb0], 16, 0, 0);
      __builtin_amdgcn_global_load_lds((gas_t*)(gA1 + ko), (las_t*)&lds[nb][0][sb1], 16, 0, 0);
      __builtin_amdgcn_global_load_lds((gas_t*)(gB0 + ko), (las_t*)&lds[nb][1][sb0], 16, 0, 0);
      __builtin_amdgcn_global_load_lds((gas_t*)(gB1 + ko), (las_t*)&lds[nb][1][sb1], 16, 0, 0);
    }
    bf16x8 af[8], bfr[4];
#pragma unroll
    for (int n = 0; n < 4; n++)
      bfr[n] = *(const bf16x8*)&lds[cur][1][(brow + n * 16) * 32 + granB];
#pragma unroll
    for (int m = 0; m < 8; m++)
      af[m] = *(const bf16x8*)&lds[cur][0][(arow + m * 16) * 32 + granA];
#pragma unroll
    for (int m = 0; m < 8; m++)
#pragma unroll
      for (int n = 0; n < 4; n++)
        acc[m][n] = __builtin_amdgcn_mfma_f32_16x16x32_bf16(af[m], bfr[n],
                                                            acc[m][n], 0, 0, 0);
    __syncthreads();  // drains: next-buf loads landed; my reads of cur done
    cur ^= 1;
  }

  float* Cf = (CMODE == 2) ? (float*)Cv + (long)blockIdx.z * zstride
                           : (float*)Cv;

  // C/D layout: col = lane&15, row = (lane>>4)*4 + reg
  const int rg = (lane >> 4) * 4;
#pragma unroll
  for (int m = 0; m < 8; m++) {
    const long gr = tm + wm * 128 + m * 16 + rg;
#pragma unroll
    for (int n = 0; n < 4; n++) {
      const long gc = tn + wn * 64 + n * 16 + lr;
#pragma unroll
      for (int r = 0; r < 4; r++) {
        if (CMODE == 1)
          ((u16*)Cv)[(gr + r) * (long)Nld + gc] = f2bf(acc[m][n][r]);
        else
          Cf[(gr + r) * (long)Nld + gc] = acc[m][n][r];
      }
    }
  }
}

// ---------------- 128x128 bf16 MFMA GEMM (m97 structure), small shapes -----
// MODE: 0 = fp32 store, 1 = softplus(x+bias) -> bf16 store,
//       2 = split-K fp32 partial store at Cv + z*zs (no atomics)
// Same conflict-free LDS swizzle as gemm256.
template <bool CLAMP_N, int MODE>
__global__ __launch_bounds__(256) void gemm_bt(const u16* __restrict__ A,
                                               const u16* __restrict__ B,
                                               void* __restrict__ Cv,
                                               const float* __restrict__ ebias,
                                               int Nv, int K, int ldc, int kc,
                                               long zs) {
  __shared__ u16 lA[128 * 32];
  __shared__ u16 lB[128 * 32];
  const int tid = threadIdx.x;
  const int lane = tid & 63, wid = tid >> 6;
  const int wm = wid >> 1, wn = wid & 1;
  const long tm = (long)blockIdx.y * 128, tn = (long)blockIdx.x * 128;

  f32x4 acc[4][4] = {};

  const int roff = lane >> 2;
  const int sks = (((lane & 3) ^ ((roff >> 1) & 3))) * 8;  // swizzled src slot
  const int c0 = wid * 2, c1 = c0 + 1;
  const long ra0 = tm + c0 * 16 + roff;
  const long ra1 = tm + c1 * 16 + roff;
  long rb0 = tn + c0 * 16 + roff;
  long rb1 = tn + c1 * 16 + roff;
  if (CLAMP_N) {
    if (rb0 >= Nv) rb0 = Nv - 1;
    if (rb1 >= Nv) rb1 = Nv - 1;
  }
  const u16* gA0 = A + ra0 * K + sks;
  const u16* gA1 = A + ra1 * K + sks;
  const u16* gB0 = B + rb0 * K + sks;
  const u16* gB1 = B + rb1 * K + sks;
  u16* sA0 = &lA[c0 * 512];
  u16* sA1 = &lA[c1 * 512];
  u16* sB0 = &lB[c0 * 512];
  u16* sB1 = &lB[c1 * 512];

  int ks0 = 0, ks1 = K;
  if (MODE == 2) { ks0 = blockIdx.z * kc; ks1 = ks0 + kc; }

  const int lr = lane & 15, kq = lane >> 4;
  const int arow = wm * 64 + lr, brow = wn * 64 + lr;
  const int granA = (kq ^ ((arow >> 1) & 3)) * 8;
  const int granB = (kq ^ ((brow >> 1) & 3)) * 8;

  for (int ks = ks0; ks < ks1; ks += 32) {
    __builtin_amdgcn_global_load_lds((gas_t*)(gA0 + ks), (las_t*)sA0, 16, 0, 0);
    __builtin_amdgcn_global_load_lds((gas_t*)(gA1 + ks), (las_t*)sA1, 16, 0, 0);
    __builtin_amdgcn_global_load_lds((gas_t*)(gB0 + ks), (las_t*)sB0, 16, 0, 0);
    __builtin_amdgcn_global_load_lds((gas_t*)(gB1 + ks), (las_t*)sB1, 16, 0, 0);
    __syncthreads();
    bf16x8 af[4], bfr[4];
#pragma unroll
    for (int i = 0; i < 4; i++) {
      af[i]  = *(const bf16x8*)&lA[(arow + i * 16) * 32 + granA];
      bfr[i] = *(const bf16x8*)&lB[(brow + i * 16) * 32 + granB];
    }
#pragma unroll
    for (int i = 0; i < 4; i++)
#pragma unroll
      for (int j = 0; j < 4; j++)
        acc[i][j] = __builtin_amdgcn_mfma_f32_16x16x32_bf16(af[i], bfr[j],
                                                            acc[i][j], 0, 0, 0);
    __syncthreads();
  }

  float* Cf = (MODE == 2) ? (float*)Cv + (long)blockIdx.z * zs : (float*)Cv;

  const int rg = (lane >> 4) * 4;
#pragma unroll
  for (int i = 0; i < 4; i++) {
    const long gr = tm + wm * 64 + i * 16 + rg;
#pragma unroll
    for (int j = 0; j < 4; j++) {
      const long gc = tn + wn * 64 + j * 16 + lr;
      if (CLAMP_N && gc >= Nv) continue;
      float bias = 0.f;
      if (MODE == 1) bias = ebias[gc];
#pragma unroll
      for (int r = 0; r < 4; r++) {
        float v = acc[i][j][r];
        if (MODE == 1)
          ((u16*)Cv)[(gr + r) * (long)ldc + gc] = f2bf(softplusf(v + bias));
        else
          Cf[(gr + r) * (long)ldc + gc] = v;
      }
    }
  }
}

// ---------------- depthwise causal conv1d (K=4) + bias + SiLU (bf16 proj) --
__global__ __launch_bounds__(256) void conv_silu_k(const u16* __restrict__ projb,
                                                   const float* __restrict__ cw,
                                                   const float* __restrict__ cb,
                                                   u16* __restrict__ ub) {
  const int idx = blockIdx.x * 256 + threadIdx.x;  // [0, 2048*4096)
  const int d = idx & (DD - 1);
  const int bl = idx >> 12;
  const int l = bl & (L_SEQ - 1);
  const float4 w = *(const float4*)(cw + d * 4);
  float s = cb[d];
  const u16* pp = projb + (long)bl * 8192 + d;
  s += w.w * bf2f(pp[0]);
  if (l >= 1) s += w.z * bf2f(pp[-8192]);
  if (l >= 2) s += w.y * bf2f(pp[-2 * 8192]);
  if (l >= 3) s += w.x * bf2f(pp[-3 * 8192]);
  const float r = s / (1.f + expf(-s));
  ub[idx] = f2bf(r);
}

// ================= chunked selective scan ==================================
__global__ __launch_bounds__(256) void scan_p1(const u16* __restrict__ dt,
                                               const u16* __restrict__ u,
                                               const float* __restrict__ ssm,
                                               const float* __restrict__ A_log,
                                               float* __restrict__ Sbuf,
                                               float* __restrict__ Pbuf) {
  __shared__ float sBC[CT * 32];
  const int tid = threadIdx.x;
  const int d = blockIdx.x * 256 + tid;
  const int c = blockIdx.y, b = blockIdx.z;
  const long blbase = (long)b * L_SEQ + (long)c * CT;
  for (int i = tid; i < CT * 32; i += 256) {
    int tt = i >> 5, j = i & 31;
    sBC[i] = ssm[(blbase + tt) * 160 + 128 + j];
  }
  __syncthreads();
  float a2[16], st[16], pr[16];
#pragma unroll
  for (int g = 0; g < 4; g++) {
    float4 al = *(const float4*)(A_log + d * 16 + g * 4);
    a2[g*4+0] = -expf(al.x) * 1.4426950408889634f;
    a2[g*4+1] = -expf(al.y) * 1.4426950408889634f;
    a2[g*4+2] = -expf(al.z) * 1.4426950408889634f;
    a2[g*4+3] = -expf(al.w) * 1.4426950408889634f;
  }
#pragma unroll
  for (int n = 0; n < 16; n++) { st[n] = 0.f; pr[n] = 1.f; }
  for (int tt = 0; tt < CT; tt++) {
    const long bl = blbase + tt;
    const float dtv = bf2f(dt[bl * DD + d]);
    const float uv = bf2f(u[bl * DD + d]);
    const float dtu = dtv * uv;
    const float4* Bv = (const float4*)&sBC[tt * 32];
#pragma unroll
    for (int g = 0; g < 4; g++) {
      const float4 Bg = Bv[g];
      float e;
      e = exp2f(a2[g*4+0]*dtv); st[g*4+0] = e*st[g*4+0] + dtu*Bg.x; pr[g*4+0] *= e;
      e = exp2f(a2[g*4+1]*dtv); st[g*4+1] = e*st[g*4+1] + dtu*Bg.y; pr[g*4+1] *= e;
      e = exp2f(a2[g*4+2]*dtv); st[g*4+2] = e*st[g*4+2] + dtu*Bg.z; pr[g*4+2] *= e;
      e = exp2f(a2[g*4+3]*dtv); st[g*4+3] = e*st[g*4+3] + dtu*Bg.w; pr[g*4+3] *= e;
    }
  }
  const long base = (((long)b * NC + c) * DD + d) * 16;
#pragma unroll
  for (int g = 0; g < 4; g++) {
    *(float4*)(Sbuf + base + g * 4) = make_float4(st[g*4+0], st[g*4+1], st[g*4+2], st[g*4+3]);
    *(float4*)(Pbuf + base + g * 4) = make_float4(pr[g*4+0], pr[g*4+1], pr[g*4+2], pr[g*4+3]);
  }
}

__global__ __launch_bounds__(256) void scan_p2(const float* __restrict__ Sbuf,
                                               const float* __restrict__ Pbuf,
                                               float* __restrict__ carry) {
  const int idx = blockIdx.x * 256 + threadIdx.x;  // < 2*4096*4
  const int ng = idx & 3;
  const int d = (idx >> 2) & (DD - 1);
  const int b = idx >> 14;
  float4 cr = make_float4(0.f, 0.f, 0.f, 0.f);
  for (int c = 0; c < NC; c++) {
    const long base = (((long)b * NC + c) * DD + d) * 16 + ng * 4;
    *(float4*)(carry + base) = cr;
    const float4 P = *(const float4*)(Pbuf + base);
    const float4 S = *(const float4*)(Sbuf + base);
    cr.x = P.x * cr.x + S.x;
    cr.y = P.y * cr.y + S.y;
    cr.z = P.z * cr.z + S.z;
    cr.w = P.w * cr.w + S.w;
  }
}

__global__ __launch_bounds__(256) void scan_p3(const u16* __restrict__ dt,
                                               const u16* __restrict__ u,
                                               const float* __restrict__ ssm,
                                               const u16* __restrict__ projb,
                                               const float* __restrict__ A_log,
                                               const float* __restrict__ Dp,
                                               const float* __restrict__ carry,
                                               u16* __restrict__ yb) {
  __shared__ float sBC[CT * 32];
  const int tid = threadIdx.x;
  const int d = blockIdx.x * 256 + tid;
  const int c = blockIdx.y, b = blockIdx.z;
  const long blbase = (long)b * L_SEQ + (long)c * CT;
  for (int i = tid; i < CT * 32; i += 256) {
    int tt = i >> 5, j = i & 31;
    sBC[i] = ssm[(blbase + tt) * 160 + 128 + j];
  }
  __syncthreads();
  float a2[16], st[16];
#pragma unroll
  for (int g = 0; g < 4; g++) {
    float4 al = *(const float4*)(A_log + d * 16 + g * 4);
    a2[g*4+0] = -expf(al.x) * 1.4426950408889634f;
    a2[g*4+1] = -expf(al.y) * 1.4426950408889634f;
    a2[g*4+2] = -expf(al.z) * 1.4426950408889634f;
    a2[g*4+3] = -expf(al.w) * 1.4426950408889634f;
  }
  const long cbase = (((long)b * NC + c) * DD + d) * 16;
#pragma unroll
  for (int g = 0; g < 4; g++) {
    float4 cv = *(const float4*)(carry + cbase + g * 4);
    st[g*4+0] = cv.x; st[g*4+1] = cv.y; st[g*4+2] = cv.z; st[g*4+3] = cv.w;
  }
  const float dp = Dp[d];
  for (int tt = 0; tt < CT; tt++) {
    const long bl = blbase + tt;
    const float dtv = bf2f(dt[bl * DD + d]);
    const float uv = bf2f(u[bl * DD + d]);
    const float dtu = dtv * uv;
    float acc = 0.f;
    const float4* Bv = (const float4*)&sBC[tt * 32];
    const float4* Cv = Bv + 4;
#pragma unroll
    for (int g = 0; g < 4; g++) {
      const float4 Bg = Bv[g];
      const float4 Cg = Cv[g];
      float e;
      e = exp2f(a2[g*4+0]*dtv); st[g*4+0] = e*st[g*4+0] + dtu*Bg.x; acc += st[g*4+0]*Cg.x;
      e = exp2f(a2[g*4+1]*dtv); st[g*4+1] = e*st[g*4+1] + dtu*Bg.y; acc += st[g*4+1]*Cg.y;
      e = exp2f(a2[g*4+2]*dtv); st[g*4+2] = e*st[g*4+2] + dtu*Bg.z; acc += st[g*4+2]*Cg.z;
      e = exp2f(a2[g*4+3]*dtv); st[g*4+3] = e*st[g*4+3] + dtu*Bg.w; acc += st[g*4+3]*Cg.w;
    }
    const float g = bf2f(projb[bl * 8192 + DD + d]);
    const float yv = (acc + uv * dp) * (g / (1.f + expf(-g)));
    yb[bl * DD + d] = f2bf(yv);
  }
}

// ---------------------------------------------------------------------------
extern "C" void kernel_launch(void* const* d_in, const int* in_sizes, int n_in,
                              void* d_out, int out_size, void* d_ws, size_t ws_size,
                              hipStream_t stream) {
  const float* hs     = (const float*)d_in[0];
  const float* w_in   = (const float*)d_in[1];
  const float* conv_w = (const float*)d_in[2];
  const float* conv_b = (const float*)d_in[3];
  const float* xw     = (const float*)d_in[4];
  const float* dtw    = (const float*)d_in[5];
  const float* dtb    = (const float*)d_in[6];
  const float* A_log  = (const float*)d_in[7];
  const float* Dp     = (const float*)d_in[8];
  const float* ow     = (const float*)d_in[9];
  float* out = (float*)d_out;

  constexpr size_t SZ_HS_BF  = 2048ull * 2048 * 2;
  constexpr size_t SZ_WIN_BF = 8192ull * 2048 * 2;
  constexpr size_t SZ_PROJ   = 2048ull * 8192 * 2;   // bf16
  constexpr size_t SZ_UBF    = 2048ull * 4096 * 2;
  constexpr size_t SZ_XW_BF  = 160ull * 4096 * 2;
  constexpr size_t SZ_SSM    = 2048ull * 160 * 4;
  constexpr size_t SZ_TS_BF  = 2048ull * 128 * 2;
  constexpr size_t SZ_DTW_BF = 4096ull * 128 * 2;
  constexpr size_t SZ_DT     = 2048ull * 4096 * 2;   // bf16
  constexpr size_t SZ_OW_BF  = 2048ull * 4096 * 2;
  constexpr size_t SZ_YBF    = 2048ull * 4096 * 2;
  constexpr size_t SZ_SCAN   = 2ull * NC * DD * 16 * 4;
  constexpr size_t SZ_PXP    = 8ull * 2048 * 160 * 4;   // x_proj partials
  constexpr size_t TOTAL = SZ_HS_BF + SZ_WIN_BF + SZ_PROJ + SZ_UBF +
                           SZ_XW_BF + SZ_SSM + SZ_TS_BF + SZ_DTW_BF + SZ_DT +
                           SZ_OW_BF + SZ_YBF + 3 * SZ_SCAN + SZ_PXP;
  if (ws_size < TOTAL) return;

  char* w = (char*)d_ws;
  u16* hs_bf   = (u16*)w;   w += SZ_HS_BF;
  u16* win_bf  = (u16*)w;   w += SZ_WIN_BF;   // dead after in_proj
  u16* projb   = (u16*)w;   w += SZ_PROJ;     // dead after scan_p3
  u16* u_bf    = (u16*)w;   w += SZ_UBF;
  u16* xw_bf   = (u16*)w;   w += SZ_XW_BF;
  float* ssm   = (float*)w; w += SZ_SSM;
  u16* ts_bf   = (u16*)w;   w += SZ_TS_BF;
  u16* dtw_bf  = (u16*)w;   w += SZ_DTW_BF;
  u16* dt_bf   = (u16*)w;   w += SZ_DT;
  u16* ow_bf   = (u16*)w;   w += SZ_OW_BF;
  u16* y_bf    = (u16*)w;   w += SZ_YBF;
  float* Sbuf  = (float*)w; w += SZ_SCAN;
  float* Pbuf  = (float*)w; w += SZ_SCAN;
  float* carry = (float*)w; w += SZ_SCAN;
  float* partsx = (float*)w; w += SZ_PXP;

  // out_proj partials: 4 x 2048x2048 fp32 = 67 MB aliasing win_bf+projb
  // (both dead once out_proj runs; stream-ordered).
  float* parts = (float*)win_bf;

  // 1) all casts, one kernel
  cast_all_k<<<29824, 256, 0, stream>>>(hs, w_in, xw, dtw, ow,
                                        hs_bf, win_bf, xw_bf, dtw_bf, ow_bf);

  // 2) in_proj (M=2048,N=8192,K=2048) -> bf16 proj
  gemm256<1, true><<<dim3(32, 8), 512, 0, stream>>>(
      hs_bf, win_bf, projb, 8192, 2048, 2048, 0);

  // 3) conv + silu -> u (bf16)
  conv_silu_k<<<32768, 256, 0, stream>>>(projb, conv_w, conv_b, u_bf);

  // 4) x_proj (M=2048,N=160,K=4096): split-K z=8 partial stores (no atomics)
  gemm_bt<true, 2><<<dim3(2, 16, 8), 256, 0, stream>>>(
      u_bf, xw_bf, partsx, nullptr, 160, 4096, 160, 512, 327680);

  // 5) reduce partials; split into ts (bf16) and ssm B/C (fp32)
  xproj_fin_k<<<1280, 256, 0, stream>>>(partsx, ts_bf, ssm);

  // 6) dt_proj (M=2048,N=4096,K=128) + fused softplus(x+bias) -> bf16
  gemm_bt<false, 1><<<dim3(32, 16), 256, 0, stream>>>(
      ts_bf, dtw_bf, dt_bf, dtb, 4096, 128, 4096, 0, 0);

  // 7) chunked selective scan
  scan_p1<<<dim3(16, NC, 2), 256, 0, stream>>>(dt_bf, u_bf, ssm, A_log, Sbuf, Pbuf);
  scan_p2<<<128, 256, 0, stream>>>(Sbuf, Pbuf, carry);
  scan_p3<<<dim3(16, NC, 2), 256, 0, stream>>>(dt_bf, u_bf, ssm, projb, A_log, Dp,
                                               carry, y_bf);

  // 8) out_proj (M=2048,N=2048,K=4096): split-K z=4 partials + reduce
  gemm256<2, false><<<dim3(8, 8, 4), 512, 0, stream>>>(
      y_bf, ow_bf, parts, 2048, 4096, 1024, 2048ll * 2048);
  reduce4_k<<<4096, 256, 0, stream>>>(parts, out, 2048ll * 2048);
}

// Round 9
// 373.680 us; speedup vs baseline: 1.0198x; 1.0198x over previous
//
#include <hip/hip_runtime.h>

#define L_SEQ 1024
#define DD 4096
#define NC 32   // scan chunks
#define CT 32   // chunk length (NC*CT == L_SEQ)

typedef short bf16x8 __attribute__((ext_vector_type(8)));
typedef float f32x4 __attribute__((ext_vector_type(4)));
typedef unsigned short u16;

typedef const __attribute__((address_space(1))) void gas_t;
typedef __attribute__((address_space(3))) void las_t;

__device__ inline u16 f2bf(float f) {
  unsigned int u = __float_as_uint(f);
  u = (u + 0x7FFFu + ((u >> 16) & 1u)) >> 16;
  return (u16)u;
}

__device__ inline float bf2f(u16 v) {
  return __uint_as_float(((unsigned int)v) << 16);
}

__device__ inline float softplusf(float x) {
  return x > 20.f ? x : log1pf(expf(x));
}

// ---------------- all 5 fp32->bf16 casts in one kernel ---------------------
__global__ __launch_bounds__(256) void cast_all_k(
    const float* __restrict__ hs, const float* __restrict__ w_in,
    const float* __restrict__ xw, const float* __restrict__ dtw,
    const float* __restrict__ ow, u16* __restrict__ hs_bf,
    u16* __restrict__ win_bf, u16* __restrict__ xw_bf,
    u16* __restrict__ dtw_bf, u16* __restrict__ ow_bf) {
  const int blk = blockIdx.x;
  const float* s;
  u16* d;
  int base;
  if (blk < 4096)        { s = hs;   d = hs_bf;  base = blk; }
  else if (blk < 20480)  { s = w_in; d = win_bf; base = blk - 4096; }
  else if (blk < 21120)  { s = xw;   d = xw_bf;  base = blk - 20480; }
  else if (blk < 21632)  { s = dtw;  d = dtw_bf; base = blk - 21120; }
  else                   { s = ow;   d = ow_bf;  base = blk - 21632; }
  const int i = (base * 256 + threadIdx.x) * 4;
  float4 v = *(const float4*)(s + i);
  ushort4 o;
  o.x = f2bf(v.x); o.y = f2bf(v.y); o.z = f2bf(v.z); o.w = f2bf(v.w);
  *(ushort4*)(d + i) = o;
}

// ---------------- reduce 4 fp32 partials -> fp32 out (float4) --------------
__global__ __launch_bounds__(256) void reduce4_k(const float* __restrict__ p,
                                                 float* __restrict__ out,
                                                 long n) {
  long i = ((long)blockIdx.x * 256 + threadIdx.x) * 4;
  if (i >= n) return;
  float4 a = *(const float4*)(p + i);
  float4 b = *(const float4*)(p + n + i);
  float4 c = *(const float4*)(p + 2 * n + i);
  float4 d = *(const float4*)(p + 3 * n + i);
  float4 o;
  o.x = (a.x + b.x) + (c.x + d.x);
  o.y = (a.y + b.y) + (c.y + d.y);
  o.z = (a.z + b.z) + (c.z + d.z);
  o.w = (a.w + b.w) + (c.w + d.w);
  *(float4*)(out + i) = o;
}

// ---------------- x_proj finalize: reduce 8 partials, split ts/ssm ---------
__global__ __launch_bounds__(256) void xproj_fin_k(const float* __restrict__ parts,
                                                   u16* __restrict__ ts,
                                                   float* __restrict__ ssm) {
  const int idx = blockIdx.x * 256 + threadIdx.x;  // < 2048*160
  float s = 0.f;
#pragma unroll
  for (int z = 0; z < 8; z++) s += parts[z * 327680 + idx];
  const int row = idx / 160;
  const int col = idx - row * 160;
  if (col < 128) ts[row * 128 + col] = f2bf(s);
  else ssm[idx] = s;
}

// ============ 256x256 BK=32 dbuf 2-phase MFMA GEMM: C = A[M,K]*B[N,K]^T ====
// 8 waves (2M x 4N), per-wave 128x64 = 8x4 frags of 16x16x32.
// LDS content swizzle (conflict-free, rule #21 both-sides):
//   LDS slot (row, granule g) holds global k-slot g ^ ((row>>1)&3).
// CMODE: 1 = bf16 store, 2 = split-K fp32 partial store (z slice at z*zstride)
template <int CMODE, bool SWZ>
__global__ __launch_bounds__(512, 2) void gemm256(const u16* __restrict__ A,
                                                  const u16* __restrict__ B,
                                                  void* __restrict__ Cv,
                                                  int Nld, int K, int kc,
                                                  long zstride) {
  __shared__ u16 lds[2][2][8192];  // [buf][0=A,1=B][256 rows * 32 k]
  const int tid = threadIdx.x;
  const int lane = tid & 63, wid = tid >> 6;
  const int wm = wid >> 2, wn = wid & 3;
  int ty = blockIdx.y, tx = blockIdx.x;
  if (SWZ) {
    int flat = blockIdx.y * 32 + blockIdx.x;
    int xcd = flat & 7, pos = flat >> 3;
    ty = (xcd & 1) * 4 + (pos >> 3);
    tx = (xcd >> 1) * 8 + (pos & 7);
  }
  const long tm = (long)ty * 256, tn = (long)tx * 256;

  const long ks0 = (CMODE == 2) ? (long)blockIdx.z * kc : 0;

  const int srow = tid >> 2;
  const int sks = (((tid & 3) ^ ((srow >> 1) & 3))) * 8;  // u16 offset
  const u16* gA0 = A + (tm + srow) * (long)K + ks0 + sks;
  const u16* gA1 = A + (tm + 128 + srow) * (long)K + ks0 + sks;
  const u16* gB0 = B + (tn + srow) * (long)K + ks0 + sks;
  const u16* gB1 = B + (tn + 128 + srow) * (long)K + ks0 + sks;
  const int sb0 = wid * 512;
  const int sb1 = 4096 + wid * 512;

  f32x4 acc[8][4] = {};

  const int lr = lane & 15, kq = lane >> 4;
  const int arow = wm * 128 + lr;
  const int brow = wn * 64 + lr;
  const int granA = (kq ^ ((arow >> 1) & 3)) * 8;
  const int granB = (kq ^ ((brow >> 1) & 3)) * 8;

  const int KT = kc >> 5;
  int cur = 0;
  __builtin_amdgcn_global_load_lds((gas_t*)gA0, (las_t*)&lds[0][0][sb0], 16, 0, 0);
  __builtin_amdgcn_global_load_lds((gas_t*)gA1, (las_t*)&lds[0][0][sb1], 16, 0, 0);
  __builtin_amdgcn_global_load_lds((gas_t*)gB0, (las_t*)&lds[0][1][sb0], 16, 0, 0);
  __builtin_amdgcn_global_load_lds((gas_t*)gB1, (las_t*)&lds[0][1][sb1], 16, 0, 0);
  __syncthreads();

  for (int kt = 0; kt < KT; ++kt) {
    if (kt + 1 < KT) {
      const long ko = (long)(kt + 1) << 5;
      const int nb = cur ^ 1;
      __builtin_amdgcn_global_load_lds((gas_t*)(gA0 + ko), (las_t*)&lds[nb][0][sb0], 16, 0, 0);
      __builtin_amdgcn_global_load_lds((gas_t*)(gA1 + ko), (las_t*)&lds[nb][0][sb1], 16, 0, 0);
      __builtin_amdgcn_global_load_lds((gas_t*)(gB0 + ko), (las_t*)&lds[nb][1][sb0], 16, 0, 0);
      __builtin_amdgcn_global_load_lds((gas_t*)(gB1 + ko), (las_t*)&lds[nb][1][sb1], 16, 0, 0);
    }
    bf16x8 af[8], bfr[4];
#pragma unroll
    for (int n = 0; n < 4; n++)
      bfr[n] = *(const bf16x8*)&lds[cur][1][(brow + n * 16) * 32 + granB];
#pragma unroll
    for (int m = 0; m < 8; m++)
      af[m] = *(const bf16x8*)&lds[cur][0][(arow + m * 16) * 32 + granA];
#pragma unroll
    for (int m = 0; m < 8; m++)
#pragma unroll
      for (int n = 0; n < 4; n++)
        acc[m][n] = __builtin_amdgcn_mfma_f32_16x16x32_bf16(af[m], bfr[n],
                                                            acc[m][n], 0, 0, 0);
    __syncthreads();
    cur ^= 1;
  }

  float* Cf = (CMODE == 2) ? (float*)Cv + (long)blockIdx.z * zstride
                           : (float*)Cv;

  const int rg = (lane >> 4) * 4;
#pragma unroll
  for (int m = 0; m < 8; m++) {
    const long gr = tm + wm * 128 + m * 16 + rg;
#pragma unroll
    for (int n = 0; n < 4; n++) {
      const long gc = tn + wn * 64 + n * 16 + lr;
#pragma unroll
      for (int r = 0; r < 4; r++) {
        if (CMODE == 1)
          ((u16*)Cv)[(gr + r) * (long)Nld + gc] = f2bf(acc[m][n][r]);
        else
          Cf[(gr + r) * (long)Nld + gc] = acc[m][n][r];
      }
    }
  }
}

// ---------------- 128x128 bf16 MFMA GEMM (m97 structure), small shapes -----
template <bool CLAMP_N, int MODE>
__global__ __launch_bounds__(256) void gemm_bt(const u16* __restrict__ A,
                                               const u16* __restrict__ B,
                                               void* __restrict__ Cv,
                                               const float* __restrict__ ebias,
                                               int Nv, int K, int ldc, int kc,
                                               long zs) {
  __shared__ u16 lA[128 * 32];
  __shared__ u16 lB[128 * 32];
  const int tid = threadIdx.x;
  const int lane = tid & 63, wid = tid >> 6;
  const int wm = wid >> 1, wn = wid & 1;
  const long tm = (long)blockIdx.y * 128, tn = (long)blockIdx.x * 128;

  f32x4 acc[4][4] = {};

  const int roff = lane >> 2;
  const int sks = (((lane & 3) ^ ((roff >> 1) & 3))) * 8;
  const int c0 = wid * 2, c1 = c0 + 1;
  const long ra0 = tm + c0 * 16 + roff;
  const long ra1 = tm + c1 * 16 + roff;
  long rb0 = tn + c0 * 16 + roff;
  long rb1 = tn + c1 * 16 + roff;
  if (CLAMP_N) {
    if (rb0 >= Nv) rb0 = Nv - 1;
    if (rb1 >= Nv) rb1 = Nv - 1;
  }
  const u16* gA0 = A + ra0 * K + sks;
  const u16* gA1 = A + ra1 * K + sks;
  const u16* gB0 = B + rb0 * K + sks;
  const u16* gB1 = B + rb1 * K + sks;
  u16* sA0 = &lA[c0 * 512];
  u16* sA1 = &lA[c1 * 512];
  u16* sB0 = &lB[c0 * 512];
  u16* sB1 = &lB[c1 * 512];

  int ks0 = 0, ks1 = K;
  if (MODE == 2) { ks0 = blockIdx.z * kc; ks1 = ks0 + kc; }

  const int lr = lane & 15, kq = lane >> 4;
  const int arow = wm * 64 + lr, brow = wn * 64 + lr;
  const int granA = (kq ^ ((arow >> 1) & 3)) * 8;
  const int granB = (kq ^ ((brow >> 1) & 3)) * 8;

  for (int ks = ks0; ks < ks1; ks += 32) {
    __builtin_amdgcn_global_load_lds((gas_t*)(gA0 + ks), (las_t*)sA0, 16, 0, 0);
    __builtin_amdgcn_global_load_lds((gas_t*)(gA1 + ks), (las_t*)sA1, 16, 0, 0);
    __builtin_amdgcn_global_load_lds((gas_t*)(gB0 + ks), (las_t*)sB0, 16, 0, 0);
    __builtin_amdgcn_global_load_lds((gas_t*)(gB1 + ks), (las_t*)sB1, 16, 0, 0);
    __syncthreads();
    bf16x8 af[4], bfr[4];
#pragma unroll
    for (int i = 0; i < 4; i++) {
      af[i]  = *(const bf16x8*)&lA[(arow + i * 16) * 32 + granA];
      bfr[i] = *(const bf16x8*)&lB[(brow + i * 16) * 32 + granB];
    }
#pragma unroll
    for (int i = 0; i < 4; i++)
#pragma unroll
      for (int j = 0; j < 4; j++)
        acc[i][j] = __builtin_amdgcn_mfma_f32_16x16x32_bf16(af[i], bfr[j],
                                                            acc[i][j], 0, 0, 0);
    __syncthreads();
  }

  float* Cf = (MODE == 2) ? (float*)Cv + (long)blockIdx.z * zs : (float*)Cv;

  const int rg = (lane >> 4) * 4;
#pragma unroll
  for (int i = 0; i < 4; i++) {
    const long gr = tm + wm * 64 + i * 16 + rg;
#pragma unroll
    for (int j = 0; j < 4; j++) {
      const long gc = tn + wn * 64 + j * 16 + lr;
      if (CLAMP_N && gc >= Nv) continue;
      float bias = 0.f;
      if (MODE == 1) bias = ebias[gc];
#pragma unroll
      for (int r = 0; r < 4; r++) {
        float v = acc[i][j][r];
        if (MODE == 1)
          ((u16*)Cv)[(gr + r) * (long)ldc + gc] = f2bf(softplusf(v + bias));
        else
          Cf[(gr + r) * (long)ldc + gc] = v;
      }
    }
  }
}

// ---------------- depthwise causal conv1d (K=4) + bias + SiLU (bf16 proj) --
__global__ __launch_bounds__(256) void conv_silu_k(const u16* __restrict__ projb,
                                                   const float* __restrict__ cw,
                                                   const float* __restrict__ cb,
                                                   u16* __restrict__ ub) {
  const int idx = blockIdx.x * 256 + threadIdx.x;  // [0, 2048*4096)
  const int d = idx & (DD - 1);
  const int bl = idx >> 12;
  const int l = bl & (L_SEQ - 1);
  const float4 w = *(const float4*)(cw + d * 4);
  float s = cb[d];
  const u16* pp = projb + (long)bl * 8192 + d;
  s += w.w * bf2f(pp[0]);
  if (l >= 1) s += w.z * bf2f(pp[-8192]);
  if (l >= 2) s += w.y * bf2f(pp[-2 * 8192]);
  if (l >= 3) s += w.x * bf2f(pp[-3 * 8192]);
  const float r = s / (1.f + expf(-s));
  ub[idx] = f2bf(r);
}

// ================= chunked selective scan ==================================
// lane split: thread = (b, chunk, d, ng); ng = tid&3 owns states [ng*4, ng*4+4).
// block = 64 d x 4 ng; grid (64, NC, 2) = 4096 blocks -> 8 waves/SIMD.
__global__ __launch_bounds__(256) void scan_p1(const u16* __restrict__ dt,
                                               const u16* __restrict__ u,
                                               const float* __restrict__ ssm,
                                               const float* __restrict__ A_log,
                                               float* __restrict__ Sbuf,
                                               float* __restrict__ Pbuf) {
  __shared__ float sBC[CT * 32];
  const int tid = threadIdx.x;
  const int ng = tid & 3;
  const int d = blockIdx.x * 64 + (tid >> 2);
  const int c = blockIdx.y, b = blockIdx.z;
  const long blbase = (long)b * L_SEQ + (long)c * CT;
  for (int i = tid; i < CT * 32; i += 256) {
    int tt = i >> 5, j = i & 31;
    sBC[i] = ssm[(blbase + tt) * 160 + 128 + j];
  }
  __syncthreads();
  const float4 al = *(const float4*)(A_log + d * 16 + ng * 4);
  const float a2x = -expf(al.x) * 1.4426950408889634f;
  const float a2y = -expf(al.y) * 1.4426950408889634f;
  const float a2z = -expf(al.z) * 1.4426950408889634f;
  const float a2w = -expf(al.w) * 1.4426950408889634f;
  float4 st = make_float4(0.f, 0.f, 0.f, 0.f);
  float4 pr = make_float4(1.f, 1.f, 1.f, 1.f);
  for (int tt = 0; tt < CT; tt++) {
    const long bl = blbase + tt;
    const float dtv = bf2f(dt[bl * DD + d]);
    const float uv = bf2f(u[bl * DD + d]);
    const float dtu = dtv * uv;
    const float4 Bg = *(const float4*)&sBC[tt * 32 + ng * 4];
    float e;
    e = exp2f(a2x * dtv); st.x = e * st.x + dtu * Bg.x; pr.x *= e;
    e = exp2f(a2y * dtv); st.y = e * st.y + dtu * Bg.y; pr.y *= e;
    e = exp2f(a2z * dtv); st.z = e * st.z + dtu * Bg.z; pr.z *= e;
    e = exp2f(a2w * dtv); st.w = e * st.w + dtu * Bg.w; pr.w *= e;
  }
  const long base = (((long)b * NC + c) * DD + d) * 16 + ng * 4;
  *(float4*)(Sbuf + base) = st;
  *(float4*)(Pbuf + base) = pr;
}

// p2: per (b,d,ng) serial over chunks; next-iter P/S prefetched.
__global__ __launch_bounds__(256) void scan_p2(const float* __restrict__ Sbuf,
                                               const float* __restrict__ Pbuf,
                                               float* __restrict__ carry) {
  const int idx = blockIdx.x * 256 + threadIdx.x;  // < 2*4096*4
  const int ng = idx & 3;
  const int d = (idx >> 2) & (DD - 1);
  const int b = idx >> 14;
  const long stride = (long)DD * 16;
  long base = ((long)b * NC * DD + d) * 16 + ng * 4;
  float4 P = *(const float4*)(Pbuf + base);
  float4 S = *(const float4*)(Sbuf + base);
  float4 cr = make_float4(0.f, 0.f, 0.f, 0.f);
  for (int c = 0; c < NC; c++) {
    float4 Pn, Sn;
    if (c + 1 < NC) {
      Pn = *(const float4*)(Pbuf + base + stride);
      Sn = *(const float4*)(Sbuf + base + stride);
    }
    *(float4*)(carry + base) = cr;
    cr.x = P.x * cr.x + S.x;
    cr.y = P.y * cr.y + S.y;
    cr.z = P.z * cr.z + S.z;
    cr.w = P.w * cr.w + S.w;
    P = Pn; S = Sn;
    base += stride;
  }
}

__global__ __launch_bounds__(256) void scan_p3(const u16* __restrict__ dt,
                                               const u16* __restrict__ u,
                                               const float* __restrict__ ssm,
                                               const u16* __restrict__ projb,
                                               const float* __restrict__ A_log,
                                               const float* __restrict__ Dp,
                                               const float* __restrict__ carry,
                                               u16* __restrict__ yb) {
  __shared__ float sBC[CT * 32];
  const int tid = threadIdx.x;
  const int ng = tid & 3;
  const int d = blockIdx.x * 64 + (tid >> 2);
  const int c = blockIdx.y, b = blockIdx.z;
  const long blbase = (long)b * L_SEQ + (long)c * CT;
  for (int i = tid; i < CT * 32; i += 256) {
    int tt = i >> 5, j = i & 31;
    sBC[i] = ssm[(blbase + tt) * 160 + 128 + j];
  }
  __syncthreads();
  const float4 al = *(const float4*)(A_log + d * 16 + ng * 4);
  const float a2x = -expf(al.x) * 1.4426950408889634f;
  const float a2y = -expf(al.y) * 1.4426950408889634f;
  const float a2z = -expf(al.z) * 1.4426950408889634f;
  const float a2w = -expf(al.w) * 1.4426950408889634f;
  float4 st = *(const float4*)(carry + (((long)b * NC + c) * DD + d) * 16 + ng * 4);
  const float dp = Dp[d];
  for (int tt = 0; tt < CT; tt++) {
    const long bl = blbase + tt;
    const float dtv = bf2f(dt[bl * DD + d]);
    const float uv = bf2f(u[bl * DD + d]);
    const float dtu = dtv * uv;
    const float4 Bg = *(const float4*)&sBC[tt * 32 + ng * 4];
    const float4 Cg = *(const float4*)&sBC[tt * 32 + 16 + ng * 4];
    float e, acc;
    e = exp2f(a2x * dtv); st.x = e * st.x + dtu * Bg.x; acc  = st.x * Cg.x;
    e = exp2f(a2y * dtv); st.y = e * st.y + dtu * Bg.y; acc += st.y * Cg.y;
    e = exp2f(a2z * dtv); st.z = e * st.z + dtu * Bg.z; acc += st.z * Cg.z;
    e = exp2f(a2w * dtv); st.w = e * st.w + dtu * Bg.w; acc += st.w * Cg.w;
    acc += __shfl_xor(acc, 1);
    acc += __shfl_xor(acc, 2);  // all 4 ng-lanes now hold the 16-state sum
    if (ng == 0) {
      const float g = bf2f(projb[bl * 8192 + DD + d]);
      const float yv = (acc + uv * dp) * (g / (1.f + expf(-g)));
      yb[bl * DD + d] = f2bf(yv);
    }
  }
}

// ---------------------------------------------------------------------------
extern "C" void kernel_launch(void* const* d_in, const int* in_sizes, int n_in,
                              void* d_out, int out_size, void* d_ws, size_t ws_size,
                              hipStream_t stream) {
  const float* hs     = (const float*)d_in[0];
  const float* w_in   = (const float*)d_in[1];
  const float* conv_w = (const float*)d_in[2];
  const float* conv_b = (const float*)d_in[3];
  const float* xw     = (const float*)d_in[4];
  const float* dtw    = (const float*)d_in[5];
  const float* dtb    = (const float*)d_in[6];
  const float* A_log  = (const float*)d_in[7];
  const float* Dp     = (const float*)d_in[8];
  const float* ow     = (const float*)d_in[9];
  float* out = (float*)d_out;

  constexpr size_t SZ_HS_BF  = 2048ull * 2048 * 2;
  constexpr size_t SZ_WIN_BF = 8192ull * 2048 * 2;
  constexpr size_t SZ_PROJ   = 2048ull * 8192 * 2;   // bf16
  constexpr size_t SZ_UBF    = 2048ull * 4096 * 2;
  constexpr size_t SZ_XW_BF  = 160ull * 4096 * 2;
  constexpr size_t SZ_SSM    = 2048ull * 160 * 4;
  constexpr size_t SZ_TS_BF  = 2048ull * 128 * 2;
  constexpr size_t SZ_DTW_BF = 4096ull * 128 * 2;
  constexpr size_t SZ_DT     = 2048ull * 4096 * 2;   // bf16
  constexpr size_t SZ_OW_BF  = 2048ull * 4096 * 2;
  constexpr size_t SZ_YBF    = 2048ull * 4096 * 2;
  constexpr size_t SZ_SCAN   = 2ull * NC * DD * 16 * 4;
  constexpr size_t SZ_PXP    = 8ull * 2048 * 160 * 4;   // x_proj partials
  constexpr size_t TOTAL = SZ_HS_BF + SZ_WIN_BF + SZ_PROJ + SZ_UBF +
                           SZ_XW_BF + SZ_SSM + SZ_TS_BF + SZ_DTW_BF + SZ_DT +
                           SZ_OW_BF + SZ_YBF + 3 * SZ_SCAN + SZ_PXP;
  if (ws_size < TOTAL) return;

  char* w = (char*)d_ws;
  u16* hs_bf   = (u16*)w;   w += SZ_HS_BF;
  u16* win_bf  = (u16*)w;   w += SZ_WIN_BF;   // dead after in_proj
  u16* projb   = (u16*)w;   w += SZ_PROJ;     // dead after scan_p3
  u16* u_bf    = (u16*)w;   w += SZ_UBF;
  u16* xw_bf   = (u16*)w;   w += SZ_XW_BF;
  float* ssm   = (float*)w; w += SZ_SSM;
  u16* ts_bf   = (u16*)w;   w += SZ_TS_BF;
  u16* dtw_bf  = (u16*)w;   w += SZ_DTW_BF;
  u16* dt_bf   = (u16*)w;   w += SZ_DT;
  u16* ow_bf   = (u16*)w;   w += SZ_OW_BF;
  u16* y_bf    = (u16*)w;   w += SZ_YBF;
  float* Sbuf  = (float*)w; w += SZ_SCAN;
  float* Pbuf  = (float*)w; w += SZ_SCAN;
  float* carry = (float*)w; w += SZ_SCAN;
  float* partsx = (float*)w; w += SZ_PXP;

  // out_proj partials alias win_bf+projb (both dead by then; stream-ordered)
  float* parts = (float*)win_bf;

  // 1) all casts, one kernel
  cast_all_k<<<29824, 256, 0, stream>>>(hs, w_in, xw, dtw, ow,
                                        hs_bf, win_bf, xw_bf, dtw_bf, ow_bf);

  // 2) in_proj (M=2048,N=8192,K=2048) -> bf16 proj
  gemm256<1, true><<<dim3(32, 8), 512, 0, stream>>>(
      hs_bf, win_bf, projb, 8192, 2048, 2048, 0);

  // 3) conv + silu -> u (bf16)
  conv_silu_k<<<32768, 256, 0, stream>>>(projb, conv_w, conv_b, u_bf);

  // 4) x_proj (M=2048,N=160,K=4096): split-K z=8 partial stores (no atomics)
  gemm_bt<true, 2><<<dim3(2, 16, 8), 256, 0, stream>>>(
      u_bf, xw_bf, partsx, nullptr, 160, 4096, 160, 512, 327680);

  // 5) reduce partials; split into ts (bf16) and ssm B/C (fp32)
  xproj_fin_k<<<1280, 256, 0, stream>>>(partsx, ts_bf, ssm);

  // 6) dt_proj (M=2048,N=4096,K=128) + fused softplus(x+bias) -> bf16
  gemm_bt<false, 1><<<dim3(32, 16), 256, 0, stream>>>(
      ts_bf, dtw_bf, dt_bf, dtb, 4096, 128, 4096, 0, 0);

  // 7) chunked selective scan (4-lane state split, 8 waves/SIMD)
  scan_p1<<<dim3(64, NC, 2), 256, 0, stream>>>(dt_bf, u_bf, ssm, A_log, Sbuf, Pbuf);
  scan_p2<<<128, 256, 0, stream>>>(Sbuf, Pbuf, carry);
  scan_p3<<<dim3(64, NC, 2), 256, 0, stream>>>(dt_bf, u_bf, ssm, projb, A_log, Dp,
                                               carry, y_bf);

  // 8) out_proj (M=2048,N=2048,K=4096): split-K z=4 partials + reduce
  gemm256<2, false><<<dim3(8, 8, 4), 512, 0, stream>>>(
      y_bf, ow_bf, parts, 2048, 4096, 1024, 2048ll * 2048);
  reduce4_k<<<4096, 256, 0, stream>>>(parts, out, 2048ll * 2048);
}

// Round 10
// 355.396 us; speedup vs baseline: 1.0723x; 1.0514x over previous
//
#include <hip/hip_runtime.h>

#define L_SEQ 1024
#define DD 4096
#define NC 32   // scan chunks
#define CT 32   // chunk length (NC*CT == L_SEQ)

typedef short bf16x8 __attribute__((ext_vector_type(8)));
typedef float f32x4 __attribute__((ext_vector_type(4)));
typedef unsigned short u16;

typedef const __attribute__((address_space(1))) void gas_t;
typedef __attribute__((address_space(3))) void las_t;

__device__ inline u16 f2bf(float f) {
  unsigned int u = __float_as_uint(f);
  u = (u + 0x7FFFu + ((u >> 16) & 1u)) >> 16;
  return (u16)u;
}

__device__ inline float bf2f(u16 v) {
  return __uint_as_float(((unsigned int)v) << 16);
}

__device__ inline float softplusf(float x) {
  return x > 20.f ? x : log1pf(expf(x));
}

// ---------------- all 5 fp32->bf16 casts in one kernel ---------------------
__global__ __launch_bounds__(256) void cast_all_k(
    const float* __restrict__ hs, const float* __restrict__ w_in,
    const float* __restrict__ xw, const float* __restrict__ dtw,
    const float* __restrict__ ow, u16* __restrict__ hs_bf,
    u16* __restrict__ win_bf, u16* __restrict__ xw_bf,
    u16* __restrict__ dtw_bf, u16* __restrict__ ow_bf) {
  const int blk = blockIdx.x;
  const float* s;
  u16* d;
  int base;
  if (blk < 4096)        { s = hs;   d = hs_bf;  base = blk; }
  else if (blk < 20480)  { s = w_in; d = win_bf; base = blk - 4096; }
  else if (blk < 21120)  { s = xw;   d = xw_bf;  base = blk - 20480; }
  else if (blk < 21632)  { s = dtw;  d = dtw_bf; base = blk - 21120; }
  else                   { s = ow;   d = ow_bf;  base = blk - 21632; }
  const int i = (base * 256 + threadIdx.x) * 4;
  float4 v = *(const float4*)(s + i);
  ushort4 o;
  o.x = f2bf(v.x); o.y = f2bf(v.y); o.z = f2bf(v.z); o.w = f2bf(v.w);
  *(ushort4*)(d + i) = o;
}

// ---------------- reduce 4 fp32 partials -> fp32 out (float4) --------------
__global__ __launch_bounds__(256) void reduce4_k(const float* __restrict__ p,
                                                 float* __restrict__ out,
                                                 long n) {
  long i = ((long)blockIdx.x * 256 + threadIdx.x) * 4;
  if (i >= n) return;
  float4 a = *(const float4*)(p + i);
  float4 b = *(const float4*)(p + n + i);
  float4 c = *(const float4*)(p + 2 * n + i);
  float4 d = *(const float4*)(p + 3 * n + i);
  float4 o;
  o.x = (a.x + b.x) + (c.x + d.x);
  o.y = (a.y + b.y) + (c.y + d.y);
  o.z = (a.z + b.z) + (c.z + d.z);
  o.w = (a.w + b.w) + (c.w + d.w);
  *(float4*)(out + i) = o;
}

// ---------------- x_proj finalize: reduce 8 partials, split ts/ssm ---------
__global__ __launch_bounds__(256) void xproj_fin_k(const float* __restrict__ parts,
                                                   u16* __restrict__ ts,
                                                   float* __restrict__ ssm) {
  const int idx = blockIdx.x * 256 + threadIdx.x;  // < 2048*160
  float s = 0.f;
#pragma unroll
  for (int z = 0; z < 8; z++) s += parts[z * 327680 + idx];
  const int row = idx / 160;
  const int col = idx - row * 160;
  if (col < 128) ts[row * 128 + col] = f2bf(s);
  else ssm[idx] = s;
}

// ============ 256x256 BK=32 dbuf 2-phase MFMA GEMM: C = A[M,K]*B[N,K]^T ====
// 8 waves (2M x 4N), per-wave 128x64 = 8x4 frags of 16x16x32.
// LDS content swizzle (conflict-free, rule #21 both-sides):
//   LDS slot (row, granule g) holds global k-slot g ^ ((row>>1)&3).
// CMODE: 1 = bf16 store, 2 = split-K fp32 partial store (z slice at z*zstride)
template <int CMODE, bool SWZ>
__global__ __launch_bounds__(512, 2) void gemm256(const u16* __restrict__ A,
                                                  const u16* __restrict__ B,
                                                  void* __restrict__ Cv,
                                                  int Nld, int K, int kc,
                                                  long zstride) {
  __shared__ u16 lds[2][2][8192];  // [buf][0=A,1=B][256 rows * 32 k]
  const int tid = threadIdx.x;
  const int lane = tid & 63, wid = tid >> 6;
  const int wm = wid >> 2, wn = wid & 3;
  int ty = blockIdx.y, tx = blockIdx.x;
  if (SWZ) {
    int flat = blockIdx.y * 32 + blockIdx.x;
    int xcd = flat & 7, pos = flat >> 3;
    ty = (xcd & 1) * 4 + (pos >> 3);
    tx = (xcd >> 1) * 8 + (pos & 7);
  }
  const long tm = (long)ty * 256, tn = (long)tx * 256;

  const long ks0 = (CMODE == 2) ? (long)blockIdx.z * kc : 0;

  const int srow = tid >> 2;
  const int sks = (((tid & 3) ^ ((srow >> 1) & 3))) * 8;  // u16 offset
  const u16* gA0 = A + (tm + srow) * (long)K + ks0 + sks;
  const u16* gA1 = A + (tm + 128 + srow) * (long)K + ks0 + sks;
  const u16* gB0 = B + (tn + srow) * (long)K + ks0 + sks;
  const u16* gB1 = B + (tn + 128 + srow) * (long)K + ks0 + sks;
  const int sb0 = wid * 512;
  const int sb1 = 4096 + wid * 512;

  f32x4 acc[8][4] = {};

  const int lr = lane & 15, kq = lane >> 4;
  const int arow = wm * 128 + lr;
  const int brow = wn * 64 + lr;
  const int granA = (kq ^ ((arow >> 1) & 3)) * 8;
  const int granB = (kq ^ ((brow >> 1) & 3)) * 8;

  const int KT = kc >> 5;
  int cur = 0;
  __builtin_amdgcn_global_load_lds((gas_t*)gA0, (las_t*)&lds[0][0][sb0], 16, 0, 0);
  __builtin_amdgcn_global_load_lds((gas_t*)gA1, (las_t*)&lds[0][0][sb1], 16, 0, 0);
  __builtin_amdgcn_global_load_lds((gas_t*)gB0, (las_t*)&lds[0][1][sb0], 16, 0, 0);
  __builtin_amdgcn_global_load_lds((gas_t*)gB1, (las_t*)&lds[0][1][sb1], 16, 0, 0);
  __syncthreads();

  for (int kt = 0; kt < KT; ++kt) {
    if (kt + 1 < KT) {
      const long ko = (long)(kt + 1) << 5;
      const int nb = cur ^ 1;
      __builtin_amdgcn_global_load_lds((gas_t*)(gA0 + ko), (las_t*)&lds[nb][0][sb0], 16, 0, 0);
      __builtin_amdgcn_global_load_lds((gas_t*)(gA1 + ko), (las_t*)&lds[nb][0][sb1], 16, 0, 0);
      __builtin_amdgcn_global_load_lds((gas_t*)(gB0 + ko), (las_t*)&lds[nb][1][sb0], 16, 0, 0);
      __builtin_amdgcn_global_load_lds((gas_t*)(gB1 + ko), (las_t*)&lds[nb][1][sb1], 16, 0, 0);
    }
    bf16x8 af[8], bfr[4];
#pragma unroll
    for (int n = 0; n < 4; n++)
      bfr[n] = *(const bf16x8*)&lds[cur][1][(brow + n * 16) * 32 + granB];
#pragma unroll
    for (int m = 0; m < 8; m++)
      af[m] = *(const bf16x8*)&lds[cur][0][(arow + m * 16) * 32 + granA];
#pragma unroll
    for (int m = 0; m < 8; m++)
#pragma unroll
      for (int n = 0; n < 4; n++)
        acc[m][n] = __builtin_amdgcn_mfma_f32_16x16x32_bf16(af[m], bfr[n],
                                                            acc[m][n], 0, 0, 0);
    __syncthreads();
    cur ^= 1;
  }

  float* Cf = (CMODE == 2) ? (float*)Cv + (long)blockIdx.z * zstride
                           : (float*)Cv;

  const int rg = (lane >> 4) * 4;
#pragma unroll
  for (int m = 0; m < 8; m++) {
    const long gr = tm + wm * 128 + m * 16 + rg;
#pragma unroll
    for (int n = 0; n < 4; n++) {
      const long gc = tn + wn * 64 + n * 16 + lr;
#pragma unroll
      for (int r = 0; r < 4; r++) {
        if (CMODE == 1)
          ((u16*)Cv)[(gr + r) * (long)Nld + gc] = f2bf(acc[m][n][r]);
        else
          Cf[(gr + r) * (long)Nld + gc] = acc[m][n][r];
      }
    }
  }
}

// ---------------- 128x128 bf16 MFMA GEMM (m97 structure), small shapes -----
template <bool CLAMP_N, int MODE>
__global__ __launch_bounds__(256) void gemm_bt(const u16* __restrict__ A,
                                               const u16* __restrict__ B,
                                               void* __restrict__ Cv,
                                               const float* __restrict__ ebias,
                                               int Nv, int K, int ldc, int kc,
                                               long zs) {
  __shared__ u16 lA[128 * 32];
  __shared__ u16 lB[128 * 32];
  const int tid = threadIdx.x;
  const int lane = tid & 63, wid = tid >> 6;
  const int wm = wid >> 1, wn = wid & 1;
  const long tm = (long)blockIdx.y * 128, tn = (long)blockIdx.x * 128;

  f32x4 acc[4][4] = {};

  const int roff = lane >> 2;
  const int sks = (((lane & 3) ^ ((roff >> 1) & 3))) * 8;
  const int c0 = wid * 2, c1 = c0 + 1;
  const long ra0 = tm + c0 * 16 + roff;
  const long ra1 = tm + c1 * 16 + roff;
  long rb0 = tn + c0 * 16 + roff;
  long rb1 = tn + c1 * 16 + roff;
  if (CLAMP_N) {
    if (rb0 >= Nv) rb0 = Nv - 1;
    if (rb1 >= Nv) rb1 = Nv - 1;
  }
  const u16* gA0 = A + ra0 * K + sks;
  const u16* gA1 = A + ra1 * K + sks;
  const u16* gB0 = B + rb0 * K + sks;
  const u16* gB1 = B + rb1 * K + sks;
  u16* sA0 = &lA[c0 * 512];
  u16* sA1 = &lA[c1 * 512];
  u16* sB0 = &lB[c0 * 512];
  u16* sB1 = &lB[c1 * 512];

  int ks0 = 0, ks1 = K;
  if (MODE == 2) { ks0 = blockIdx.z * kc; ks1 = ks0 + kc; }

  const int lr = lane & 15, kq = lane >> 4;
  const int arow = wm * 64 + lr, brow = wn * 64 + lr;
  const int granA = (kq ^ ((arow >> 1) & 3)) * 8;
  const int granB = (kq ^ ((brow >> 1) & 3)) * 8;

  for (int ks = ks0; ks < ks1; ks += 32) {
    __builtin_amdgcn_global_load_lds((gas_t*)(gA0 + ks), (las_t*)sA0, 16, 0, 0);
    __builtin_amdgcn_global_load_lds((gas_t*)(gA1 + ks), (las_t*)sA1, 16, 0, 0);
    __builtin_amdgcn_global_load_lds((gas_t*)(gB0 + ks), (las_t*)sB0, 16, 0, 0);
    __builtin_amdgcn_global_load_lds((gas_t*)(gB1 + ks), (las_t*)sB1, 16, 0, 0);
    __syncthreads();
    bf16x8 af[4], bfr[4];
#pragma unroll
    for (int i = 0; i < 4; i++) {
      af[i]  = *(const bf16x8*)&lA[(arow + i * 16) * 32 + granA];
      bfr[i] = *(const bf16x8*)&lB[(brow + i * 16) * 32 + granB];
    }
#pragma unroll
    for (int i = 0; i < 4; i++)
#pragma unroll
      for (int j = 0; j < 4; j++)
        acc[i][j] = __builtin_amdgcn_mfma_f32_16x16x32_bf16(af[i], bfr[j],
                                                            acc[i][j], 0, 0, 0);
    __syncthreads();
  }

  float* Cf = (MODE == 2) ? (float*)Cv + (long)blockIdx.z * zs : (float*)Cv;

  const int rg = (lane >> 4) * 4;
#pragma unroll
  for (int i = 0; i < 4; i++) {
    const long gr = tm + wm * 64 + i * 16 + rg;
#pragma unroll
    for (int j = 0; j < 4; j++) {
      const long gc = tn + wn * 64 + j * 16 + lr;
      if (CLAMP_N && gc >= Nv) continue;
      float bias = 0.f;
      if (MODE == 1) bias = ebias[gc];
#pragma unroll
      for (int r = 0; r < 4; r++) {
        float v = acc[i][j][r];
        if (MODE == 1)
          ((u16*)Cv)[(gr + r) * (long)ldc + gc] = f2bf(softplusf(v + bias));
        else
          Cf[(gr + r) * (long)ldc + gc] = v;
      }
    }
  }
}

// ---------------- depthwise causal conv1d (K=4) + bias + SiLU (bf16 proj) --
__global__ __launch_bounds__(256) void conv_silu_k(const u16* __restrict__ projb,
                                                   const float* __restrict__ cw,
                                                   const float* __restrict__ cb,
                                                   u16* __restrict__ ub) {
  const int idx = blockIdx.x * 256 + threadIdx.x;  // [0, 2048*4096)
  const int d = idx & (DD - 1);
  const int bl = idx >> 12;
  const int l = bl & (L_SEQ - 1);
  const float4 w = *(const float4*)(cw + d * 4);
  float s = cb[d];
  const u16* pp = projb + (long)bl * 8192 + d;
  s += w.w * bf2f(pp[0]);
  if (l >= 1) s += w.z * bf2f(pp[-8192]);
  if (l >= 2) s += w.y * bf2f(pp[-2 * 8192]);
  if (l >= 3) s += w.x * bf2f(pp[-3 * 8192]);
  const float r = s / (1.f + expf(-s));
  ub[idx] = f2bf(r);
}

// ================= chunked selective scan ==================================
// thread-per-d (256 d/block); dt/u tiles LDS-staged with coalesced uint4
// loads (one latency exposure), inner loop reads LDS only (2 lanes/bank =
// free); B/C reads are wave-uniform -> broadcast.
__global__ __launch_bounds__(256) void scan_p1(const u16* __restrict__ dt,
                                               const u16* __restrict__ u,
                                               const float* __restrict__ ssm,
                                               const float* __restrict__ A_log,
                                               float* __restrict__ Sbuf,
                                               float* __restrict__ Pbuf) {
  __shared__ float sBC[CT * 32];   // 4KB
  __shared__ u16 dtl[CT][256];     // 16KB
  __shared__ u16 ul[CT][256];      // 16KB
  const int tid = threadIdx.x;
  const int d0 = blockIdx.x * 256;
  const int d = d0 + tid;
  const int c = blockIdx.y, b = blockIdx.z;
  const long blbase = (long)b * L_SEQ + (long)c * CT;
  for (int i = tid; i < CT * 32; i += 256) {
    int tt = i >> 5, j = i & 31;
    sBC[i] = ssm[(blbase + tt) * 160 + 128 + j];
  }
  const u16* dtg = dt + blbase * DD + d0;
  const u16* ug  = u  + blbase * DD + d0;
#pragma unroll
  for (int it = 0; it < 4; ++it) {
    const int ck = it * 256 + tid;
    const int row = ck >> 5, ch = (ck & 31) * 8;
    *(uint4*)&dtl[row][ch] = *(const uint4*)(dtg + (long)row * DD + ch);
    *(uint4*)&ul[row][ch]  = *(const uint4*)(ug  + (long)row * DD + ch);
  }
  __syncthreads();
  float a2[16], st[16], pr[16];
#pragma unroll
  for (int g = 0; g < 4; g++) {
    float4 al = *(const float4*)(A_log + d * 16 + g * 4);
    a2[g*4+0] = -expf(al.x) * 1.4426950408889634f;
    a2[g*4+1] = -expf(al.y) * 1.4426950408889634f;
    a2[g*4+2] = -expf(al.z) * 1.4426950408889634f;
    a2[g*4+3] = -expf(al.w) * 1.4426950408889634f;
  }
#pragma unroll
  for (int n = 0; n < 16; n++) { st[n] = 0.f; pr[n] = 1.f; }
  for (int tt = 0; tt < CT; tt++) {
    const float dtv = bf2f(dtl[tt][tid]);
    const float uv = bf2f(ul[tt][tid]);
    const float dtu = dtv * uv;
    const float4* Bv = (const float4*)&sBC[tt * 32];
#pragma unroll
    for (int g = 0; g < 4; g++) {
      const float4 Bg = Bv[g];
      float e;
      e = exp2f(a2[g*4+0]*dtv); st[g*4+0] = e*st[g*4+0] + dtu*Bg.x; pr[g*4+0] *= e;
      e = exp2f(a2[g*4+1]*dtv); st[g*4+1] = e*st[g*4+1] + dtu*Bg.y; pr[g*4+1] *= e;
      e = exp2f(a2[g*4+2]*dtv); st[g*4+2] = e*st[g*4+2] + dtu*Bg.z; pr[g*4+2] *= e;
      e = exp2f(a2[g*4+3]*dtv); st[g*4+3] = e*st[g*4+3] + dtu*Bg.w; pr[g*4+3] *= e;
    }
  }
  const long base = (((long)b * NC + c) * DD + d) * 16;
#pragma unroll
  for (int g = 0; g < 4; g++) {
    *(float4*)(Sbuf + base + g * 4) = make_float4(st[g*4+0], st[g*4+1], st[g*4+2], st[g*4+3]);
    *(float4*)(Pbuf + base + g * 4) = make_float4(pr[g*4+0], pr[g*4+1], pr[g*4+2], pr[g*4+3]);
  }
}

// p2: per (b,d,ng) serial over chunks; next-iter P/S prefetched.
__global__ __launch_bounds__(256) void scan_p2(const float* __restrict__ Sbuf,
                                               const float* __restrict__ Pbuf,
                                               float* __restrict__ carry) {
  const int idx = blockIdx.x * 256 + threadIdx.x;  // < 2*4096*4
  const int ng = idx & 3;
  const int d = (idx >> 2) & (DD - 1);
  const int b = idx >> 14;
  const long stride = (long)DD * 16;
  long base = ((long)b * NC * DD + d) * 16 + ng * 4;
  float4 P = *(const float4*)(Pbuf + base);
  float4 S = *(const float4*)(Sbuf + base);
  float4 cr = make_float4(0.f, 0.f, 0.f, 0.f);
  for (int c = 0; c < NC; c++) {
    float4 Pn, Sn;
    if (c + 1 < NC) {
      Pn = *(const float4*)(Pbuf + base + stride);
      Sn = *(const float4*)(Sbuf + base + stride);
    }
    *(float4*)(carry + base) = cr;
    cr.x = P.x * cr.x + S.x;
    cr.y = P.y * cr.y + S.y;
    cr.z = P.z * cr.z + S.z;
    cr.w = P.w * cr.w + S.w;
    P = Pn; S = Sn;
    base += stride;
  }
}

__global__ __launch_bounds__(256) void scan_p3(const u16* __restrict__ dt,
                                               const u16* __restrict__ u,
                                               const float* __restrict__ ssm,
                                               const u16* __restrict__ projb,
                                               const float* __restrict__ A_log,
                                               const float* __restrict__ Dp,
                                               const float* __restrict__ carry,
                                               u16* __restrict__ yb) {
  __shared__ float sBC[CT * 32];
  __shared__ u16 dtl[CT][256];
  __shared__ u16 ul[CT][256];
  const int tid = threadIdx.x;
  const int d0 = blockIdx.x * 256;
  const int d = d0 + tid;
  const int c = blockIdx.y, b = blockIdx.z;
  const long blbase = (long)b * L_SEQ + (long)c * CT;
  for (int i = tid; i < CT * 32; i += 256) {
    int tt = i >> 5, j = i & 31;
    sBC[i] = ssm[(blbase + tt) * 160 + 128 + j];
  }
  const u16* dtg = dt + blbase * DD + d0;
  const u16* ug  = u  + blbase * DD + d0;
#pragma unroll
  for (int it = 0; it < 4; ++it) {
    const int ck = it * 256 + tid;
    const int row = ck >> 5, ch = (ck & 31) * 8;
    *(uint4*)&dtl[row][ch] = *(const uint4*)(dtg + (long)row * DD + ch);
    *(uint4*)&ul[row][ch]  = *(const uint4*)(ug  + (long)row * DD + ch);
  }
  __syncthreads();
  float a2[16], st[16];
#pragma unroll
  for (int g = 0; g < 4; g++) {
    float4 al = *(const float4*)(A_log + d * 16 + g * 4);
    a2[g*4+0] = -expf(al.x) * 1.4426950408889634f;
    a2[g*4+1] = -expf(al.y) * 1.4426950408889634f;
    a2[g*4+2] = -expf(al.z) * 1.4426950408889634f;
    a2[g*4+3] = -expf(al.w) * 1.4426950408889634f;
  }
  const long cbase = (((long)b * NC + c) * DD + d) * 16;
#pragma unroll
  for (int g = 0; g < 4; g++) {
    float4 cv = *(const float4*)(carry + cbase + g * 4);
    st[g*4+0] = cv.x; st[g*4+1] = cv.y; st[g*4+2] = cv.z; st[g*4+3] = cv.w;
  }
  const float dp = Dp[d];
  const u16* gp = projb + blbase * 8192 + DD + d;
  u16 gnext = gp[0];
  for (int tt = 0; tt < CT; tt++) {
    const u16 gcur = gnext;
    if (tt + 1 < CT) gnext = gp[(tt + 1) * 8192];  // prefetch next gate
    const float dtv = bf2f(dtl[tt][tid]);
    const float uv = bf2f(ul[tt][tid]);
    const float dtu = dtv * uv;
    float acc = 0.f;
    const float4* Bv = (const float4*)&sBC[tt * 32];
    const float4* Cv = Bv + 4;
#pragma unroll
    for (int g = 0; g < 4; g++) {
      const float4 Bg = Bv[g];
      const float4 Cg = Cv[g];
      float e;
      e = exp2f(a2[g*4+0]*dtv); st[g*4+0] = e*st[g*4+0] + dtu*Bg.x; acc += st[g*4+0]*Cg.x;
      e = exp2f(a2[g*4+1]*dtv); st[g*4+1] = e*st[g*4+1] + dtu*Bg.y; acc += st[g*4+1]*Cg.y;
      e = exp2f(a2[g*4+2]*dtv); st[g*4+2] = e*st[g*4+2] + dtu*Bg.z; acc += st[g*4+2]*Cg.z;
      e = exp2f(a2[g*4+3]*dtv); st[g*4+3] = e*st[g*4+3] + dtu*Bg.w; acc += st[g*4+3]*Cg.w;
    }
    const float g = bf2f(gcur);
    const float yv = (acc + uv * dp) * (g / (1.f + expf(-g)));
    yb[(blbase + tt) * DD + d] = f2bf(yv);
  }
}

// ---------------------------------------------------------------------------
extern "C" void kernel_launch(void* const* d_in, const int* in_sizes, int n_in,
                              void* d_out, int out_size, void* d_ws, size_t ws_size,
                              hipStream_t stream) {
  const float* hs     = (const float*)d_in[0];
  const float* w_in   = (const float*)d_in[1];
  const float* conv_w = (const float*)d_in[2];
  const float* conv_b = (const float*)d_in[3];
  const float* xw     = (const float*)d_in[4];
  const float* dtw    = (const float*)d_in[5];
  const float* dtb    = (const float*)d_in[6];
  const float* A_log  = (const float*)d_in[7];
  const float* Dp     = (const float*)d_in[8];
  const float* ow     = (const float*)d_in[9];
  float* out = (float*)d_out;

  constexpr size_t SZ_HS_BF  = 2048ull * 2048 * 2;
  constexpr size_t SZ_WIN_BF = 8192ull * 2048 * 2;
  constexpr size_t SZ_PROJ   = 2048ull * 8192 * 2;   // bf16
  constexpr size_t SZ_UBF    = 2048ull * 4096 * 2;
  constexpr size_t SZ_XW_BF  = 160ull * 4096 * 2;
  constexpr size_t SZ_SSM    = 2048ull * 160 * 4;
  constexpr size_t SZ_TS_BF  = 2048ull * 128 * 2;
  constexpr size_t SZ_DTW_BF = 4096ull * 128 * 2;
  constexpr size_t SZ_DT     = 2048ull * 4096 * 2;   // bf16
  constexpr size_t SZ_OW_BF  = 2048ull * 4096 * 2;
  constexpr size_t SZ_YBF    = 2048ull * 4096 * 2;
  constexpr size_t SZ_SCAN   = 2ull * NC * DD * 16 * 4;
  constexpr size_t SZ_PXP    = 8ull * 2048 * 160 * 4;   // x_proj partials
  constexpr size_t TOTAL = SZ_HS_BF + SZ_WIN_BF + SZ_PROJ + SZ_UBF +
                           SZ_XW_BF + SZ_SSM + SZ_TS_BF + SZ_DTW_BF + SZ_DT +
                           SZ_OW_BF + SZ_YBF + 3 * SZ_SCAN + SZ_PXP;
  if (ws_size < TOTAL) return;

  char* w = (char*)d_ws;
  u16* hs_bf   = (u16*)w;   w += SZ_HS_BF;
  u16* win_bf  = (u16*)w;   w += SZ_WIN_BF;   // dead after in_proj
  u16* projb   = (u16*)w;   w += SZ_PROJ;     // dead after scan_p3
  u16* u_bf    = (u16*)w;   w += SZ_UBF;
  u16* xw_bf   = (u16*)w;   w += SZ_XW_BF;
  float* ssm   = (float*)w; w += SZ_SSM;
  u16* ts_bf   = (u16*)w;   w += SZ_TS_BF;
  u16* dtw_bf  = (u16*)w;   w += SZ_DTW_BF;
  u16* dt_bf   = (u16*)w;   w += SZ_DT;
  u16* ow_bf   = (u16*)w;   w += SZ_OW_BF;
  u16* y_bf    = (u16*)w;   w += SZ_YBF;
  float* Sbuf  = (float*)w; w += SZ_SCAN;
  float* Pbuf  = (float*)w; w += SZ_SCAN;
  float* carry = (float*)w; w += SZ_SCAN;
  float* partsx = (float*)w; w += SZ_PXP;

  // out_proj partials alias win_bf+projb (both dead by then; stream-ordered)
  float* parts = (float*)win_bf;

  // 1) all casts, one kernel
  cast_all_k<<<29824, 256, 0, stream>>>(hs, w_in, xw, dtw, ow,
                                        hs_bf, win_bf, xw_bf, dtw_bf, ow_bf);

  // 2) in_proj (M=2048,N=8192,K=2048) -> bf16 proj
  gemm256<1, true><<<dim3(32, 8), 512, 0, stream>>>(
      hs_bf, win_bf, projb, 8192, 2048, 2048, 0);

  // 3) conv + silu -> u (bf16)
  conv_silu_k<<<32768, 256, 0, stream>>>(projb, conv_w, conv_b, u_bf);

  // 4) x_proj (M=2048,N=160,K=4096): split-K z=8 partial stores (no atomics)
  gemm_bt<true, 2><<<dim3(2, 16, 8), 256, 0, stream>>>(
      u_bf, xw_bf, partsx, nullptr, 160, 4096, 160, 512, 327680);

  // 5) reduce partials; split into ts (bf16) and ssm B/C (fp32)
  xproj_fin_k<<<1280, 256, 0, stream>>>(partsx, ts_bf, ssm);

  // 6) dt_proj (M=2048,N=4096,K=128) + fused softplus(x+bias) -> bf16
  gemm_bt<false, 1><<<dim3(32, 16), 256, 0, stream>>>(
      ts_bf, dtw_bf, dt_bf, dtb, 4096, 128, 4096, 0, 0);

  // 7) chunked selective scan (thread-per-d, LDS-staged dt/u)
  scan_p1<<<dim3(16, NC, 2), 256, 0, stream>>>(dt_bf, u_bf, ssm, A_log, Sbuf, Pbuf);
  scan_p2<<<128, 256, 0, stream>>>(Sbuf, Pbuf, carry);
  scan_p3<<<dim3(16, NC, 2), 256, 0, stream>>>(dt_bf, u_bf, ssm, projb, A_log, Dp,
                                               carry, y_bf);

  // 8) out_proj (M=2048,N=2048,K=4096): split-K z=4 partials + reduce
  gemm256<2, false><<<dim3(8, 8, 4), 512, 0, stream>>>(
      y_bf, ow_bf, parts, 2048, 4096, 1024, 2048ll * 2048);
  reduce4_k<<<4096, 256, 0, stream>>>(parts, out, 2048ll * 2048);
}